// Round 9
// baseline (682.141 us; speedup 1.0000x reference)
//
#include <hip/hip_runtime.h>
#include <hip/hip_cooperative_groups.h>
#include <hip/hip_bf16.h>
#include <math.h>

// MultiLayerGRUParallel: B=32, S=4096, H=128, OUT=128, L=3
// r8 pipeline with the three scan-class kernels (kb, kb, scan3v2) fused into
// ONE cooperative kernel with grid syncs. Purpose: (a) surface the dominant
// phase above the 160us harness fills so rocprof top-5 finally shows its
// counters; (b) remove 2 kernel boundaries. Host falls back to the proven
// separate kernels if cooperative occupancy/launch is unavailable.
// Pipeline: prep0c -> scans(coop; or kb,kb,scan3v2) -> outmm -> outred.
#define B_   32
#define S_   4096
#define H_   128
#define OUT_ 128
#define P_   (B_*S_)       // 131072 positions
#define NC_  64            // time chunks per chain
#define CH_  (S_/NC_)      // 64 steps per chunk
#define NKS_ 512           // split-K workgroups for final matmul
#define KTOT_ (H_*S_)      // 524288
#define NEGINF_ (-__builtin_inff())
#define HTP_ 136           // hT row pitch (ushorts): 272B -> row bank rotates by 4
#define LOGHALF_ (-0.6931471805599453f)

namespace cg = cooperative_groups;

typedef __bf16 bf16x8 __attribute__((ext_vector_type(8)));
typedef float  f32x4  __attribute__((ext_vector_type(4)));
typedef unsigned short ushort8_t __attribute__((ext_vector_type(8)));

// ---- fast math (|args| bounded <~10 in this net; tolerance 5.2e-2) ----
__device__ __forceinline__ float sp_(float x) {            // softplus
  return __logf(1.f + __expf(x));
}
__device__ __forceinline__ float logg_(float x) {          // _log_g
  float t = (x >= 0.f) ? (x + 0.5f) : __builtin_amdgcn_rcpf(1.f + __expf(-x));
  return __logf(t);
}
__device__ __forceinline__ float lae_(float a, float b) {  // logaddexp
  float m = fmaxf(a, b);
  float d = -fabsf(a - b);                 // lae(-inf,x)=x fine
  return m + __logf(1.f + __expf(d));
}
__device__ __forceinline__ float sigm_(float e) {          // sigmoid
  return __builtin_amdgcn_rcpf(1.f + __expf(-e));
}
__device__ __forceinline__ unsigned short f2bf_(float f) { // fp32->bf16 RNE
  unsigned int u = __float_as_uint(f);
  u += 0x7fffu + ((u >> 16) & 1u);
  return (unsigned short)(u >> 16);
}

// DPP inclusive add-scan over 64 lanes: 6 VALU ops, no LDS pipe.
#define DPPADD_(v, ctrl, rmask) \
  ((v) + __int_as_float(__builtin_amdgcn_update_dpp( \
      0, __float_as_int(v), (ctrl), (rmask), 0xf, true)))
__device__ __forceinline__ float wscan_(float v) {
  v = DPPADD_(v, 0x111, 0xf);  // row_shr:1
  v = DPPADD_(v, 0x112, 0xf);  // row_shr:2
  v = DPPADD_(v, 0x114, 0xf);  // row_shr:4
  v = DPPADD_(v, 0x118, 0xf);  // row_shr:8
  v = DPPADD_(v, 0x142, 0xa);  // row_bcast:15 -> rows 1,3
  v = DPPADD_(v, 0x143, 0xc);  // row_bcast:31 -> rows 2,3
  return v;
}

// ua layout: float2 {u, A} per (position, channel):
//   ua[blk*16384 + pos_in_chunk*256 + 2*ch + {0,1}]

// ---------------- layer 0 prep + chunk totals (+ weight convert tail) -------
__global__ __launch_bounds__(256) void prep0c_kernel(
    const float* __restrict__ x,
    const float* __restrict__ Wz, const float* __restrict__ bz,
    const float* __restrict__ Wh, const float* __restrict__ bh,
    float* __restrict__ ua, float* __restrict__ tot,
    const float* __restrict__ Wz1, const float* __restrict__ Wh1,
    const float* __restrict__ Wz2, const float* __restrict__ Wh2,
    unsigned short* __restrict__ Wc1, unsigned short* __restrict__ Wc2)
{
  __shared__ float tpart[4][128];
  if (blockIdx.x >= 2048) {            // weight-convert tail blocks
    int idx = (blockIdx.x - 2048) * 256 + threadIdx.x;  // < 32768
    Wc1[idx] = f2bf_(idx < 16384 ? Wz1[idx] : Wh1[idx - 16384]);
    Wc2[idx] = f2bf_(idx < 16384 ? Wz2[idx] : Wh2[idx - 16384]);
    return;
  }
  int lane = threadIdx.x & 63, w = threadIdx.x >> 6;
  float wz0 = Wz[lane], wz1 = Wz[lane + 64];
  float bz0 = bz[lane], bz1 = bz[lane + 64];
  float wh0 = Wh[lane], wh1 = Wh[lane + 64];
  float bh0 = bh[lane], bh1 = bh[lane + 64];
  int blk = blockIdx.x;                       // b*NC + c
  size_t base2 = (size_t)blk * (CH_ * 256);
  int pos0 = blk * CH_;
  float xv[16];
  #pragma unroll
  for (int j = 0; j < 16; ++j) xv[j] = x[pos0 + j * 4 + w];
  float t0 = NEGINF_, t1 = NEGINF_;
  #pragma unroll
  for (int j = 0; j < 16; ++j) {
    int i = j * 4 + w;
    float k0 = fmaf(xv[j], wz0, bz0), k1 = fmaf(xv[j], wz1, bz1);
    float g0 = fmaf(xv[j], wh0, bh0), g1 = fmaf(xv[j], wh1, bh1);
    float lc0 = -sp_(k0), lc1 = -sp_(k1);
    float lv0 = k0 + lc0 + logg_(g0);   // -sp(-k) == k - sp(k)
    float lv1 = k1 + lc1 + logg_(g1);
    float s0 = wscan_(lc0);
    float c0 = __shfl(s0, 63, 64);
    float s1 = wscan_(lc1) + c0;
    float u0 = lv0 - s0, u1 = lv1 - s1;
    size_t o2 = base2 + (size_t)i * 256;
    *reinterpret_cast<float2*>(&ua[o2 + 2 * lane])       = make_float2(u0, s0);
    *reinterpret_cast<float2*>(&ua[o2 + 128 + 2 * lane]) = make_float2(u1, s1);
    t0 = lae_(t0, u0); t1 = lae_(t1, u1);
  }
  tpart[w][lane] = t0; tpart[w][64 + lane] = t1;
  __syncthreads();
  if (w == 0) {
    int ch = lane;
    tot[(size_t)blk * H_ + ch] =
        lae_(lae_(tpart[0][ch], tpart[1][ch]), lae_(tpart[2][ch], tpart[3][ch]));
    ch = lane + 64;
    tot[(size_t)blk * H_ + ch] =
        lae_(lae_(tpart[0][ch], tpart[1][ch]), lae_(tpart[2][ch], tpart[3][ch]));
  }
}

// ---------------- kb body: carry + h(layer l) + MFMA + epilogue -------------
// 16-batch phase-1 loads (register-pressure capped for __launch_bounds__(.,4)).
__device__ __forceinline__ void kb_body(
    const float* __restrict__ totIn, const unsigned short* __restrict__ Wc,
    const float* __restrict__ bz, const float* __restrict__ bh,
    float* __restrict__ ua, float* __restrict__ totOut, int blk,
    unsigned short (*hT)[HTP_], float* ksu, float* thand, float (*tpart)[128])
{
  int tid = threadIdx.x;
  int lane = tid & 63, w = tid >> 6;
  int l15 = lane & 15, quad = lane >> 4;
  int half = tid >> 7, ch = tid & 127;
  int cidx = blk & (NC_ - 1);
  size_t base2 = (size_t)blk * (CH_ * 256);

  // ---- carry preamble: reduce totIn[chain, 0..cidx-1, ch] ----
  {
    const float* tp = totIn + (size_t)(blk - cidx) * H_ + ch;
    float p0 = NEGINF_, p1 = NEGINF_;
    int i = half;
    for (; i + 2 < cidx; i += 4) {
      float a0 = tp[(size_t)i * H_];
      float a1 = tp[(size_t)(i + 2) * H_];
      p0 = lae_(p0, a0); p1 = lae_(p1, a1);
    }
    for (; i < cidx; i += 2) p0 = lae_(p0, tp[(size_t)i * H_]);
    tpart[half * 2][ch] = p0; tpart[half * 2 + 1][ch] = p1;
  }
  __syncthreads();

  const float* stp = ua + base2 + 2 * ch;

  // ---- phase 1a ----
  if (half == 0) {
    float r = LOGHALF_;
    r = lae_(r, tpart[0][ch]); r = lae_(r, tpart[1][ch]);
    r = lae_(r, tpart[2][ch]); r = lae_(r, tpart[3][ch]);
    for (int i0 = 0; i0 < 32; i0 += 16) {
      float uv[16], av[16];
      #pragma unroll
      for (int i = 0; i < 16; ++i) {
        float2 v = *reinterpret_cast<const float2*>(stp + (size_t)(i0 + i) * 256);
        uv[i] = v.x; av[i] = v.y;
      }
      #pragma unroll
      for (int i = 0; i < 16; ++i) {
        r = lae_(r, uv[i]);
        hT[i0 + i][ch] = f2bf_(sigm_(__expf(av[i] + r)));
      }
    }
    thand[ch] = r;   // carry into position 32
  } else {
    float r = NEGINF_;
    for (int i0 = 0; i0 < 32; i0 += 16) {
      float uv[16];
      #pragma unroll
      for (int i = 0; i < 16; ++i) uv[i] = stp[(size_t)(32 + i0 + i) * 256];
      #pragma unroll
      for (int i = 0; i < 16; ++i) { r = lae_(r, uv[i]); ksu[(i0 + i) * 128 + ch] = r; }
    }
  }
  __syncthreads();
  // ---- phase 1b: half1 fixup with half0's carry ----
  if (half == 1) {
    float r31 = thand[ch];
    for (int i0 = 0; i0 < 32; i0 += 16) {
      float av[16];
      #pragma unroll
      for (int i = 0; i < 16; ++i) av[i] = stp[(size_t)(32 + i0 + i) * 256 + 1];
      #pragma unroll
      for (int i = 0; i < 16; ++i) {
        float ri = lae_(r31, ksu[(i0 + i) * 128 + ch]);
        hT[32 + i0 + i][ch] = f2bf_(sigm_(__expf(av[i] + ri)));
      }
    }
  }
  __syncthreads();

  float bz0v = bz[lane], bz1v = bz[lane + 64];
  float bh0v = bh[lane], bh1v = bh[lane + 64];
  float t0 = NEGINF_, t1 = NEGINF_;

  // ---- phase 2/3 per 16-row m-tile: MFMA then epilogue ----
  for (int t = 0; t < 4; ++t) {
    f32x4 z = {0.f, 0.f, 0.f, 0.f};
    f32x4 acc[4] = {z, z, z, z};
    #pragma unroll
    for (int kk = 0; kk < 4; ++kk) {
      bf16x8 a = *reinterpret_cast<const bf16x8*>(&hT[t * 16 + l15][kk * 32 + quad * 8]);
      #pragma unroll
      for (int nt = 0; nt < 4; ++nt) {
        int n = w * 64 + nt * 16 + l15;
        bf16x8 bfv = *reinterpret_cast<const bf16x8*>(Wc + n * 128 + kk * 32 + quad * 8);
        acc[nt] = __builtin_amdgcn_mfma_f32_16x16x32_bf16(a, bfv, acc[nt], 0, 0, 0);
      }
    }
    __syncthreads();  // previous epilogue done reading kg (tile 0: scr dead)
    #pragma unroll
    for (int nt = 0; nt < 4; ++nt) {
      int col = w * 64 + nt * 16 + l15;
      #pragma unroll
      for (int r2 = 0; r2 < 4; ++r2)
        ksu[(quad * 4 + r2) * 260 + col] = acc[nt][r2];   // D: row=quad*4+r2
    }
    __syncthreads();
    #pragma unroll
    for (int i = 0; i < 4; ++i) {
      int row = w + i * 4;            // wave-interleaved rows of the m-tile
      int sIdx = t * 16 + row;
      float k0 = ksu[row * 260 + lane]        + bz0v;
      float k1 = ksu[row * 260 + 64 + lane]   + bz1v;
      float g0 = ksu[row * 260 + 128 + lane]  + bh0v;
      float g1 = ksu[row * 260 + 192 + lane]  + bh1v;
      float lc0 = -sp_(k0), lc1 = -sp_(k1);
      float lv0 = k0 + lc0 + logg_(g0);
      float lv1 = k1 + lc1 + logg_(g1);
      float s0 = wscan_(lc0);
      float c0 = __shfl(s0, 63, 64);
      float s1 = wscan_(lc1) + c0;
      float u0 = lv0 - s0, u1 = lv1 - s1;
      size_t o2 = base2 + (size_t)sIdx * 256;
      *reinterpret_cast<float2*>(&ua[o2 + 2 * lane])       = make_float2(u0, s0);
      *reinterpret_cast<float2*>(&ua[o2 + 128 + 2 * lane]) = make_float2(u1, s1);
      t0 = lae_(t0, u0); t1 = lae_(t1, u1);
    }
  }

  // ---- combine chunk totals across the 4 waves ----
  tpart[w][lane] = t0; tpart[w][64 + lane] = t1;
  __syncthreads();
  if (w == 0) {
    int c = lane;
    totOut[(size_t)blk * H_ + c] =
        lae_(lae_(tpart[0][c], tpart[1][c]), lae_(tpart[2][c], tpart[3][c]));
    c = lane + 64;
    totOut[(size_t)blk * H_ + c] =
        lae_(lae_(tpart[0][c], tpart[1][c]), lae_(tpart[2][c], tpart[3][c]));
  }
}

// ---------------- scan3 body: layer-2 final scan -> hbf (bf16) --------------
__device__ __forceinline__ void scan3_body(
    const float* __restrict__ ua, const float* __restrict__ totIn,
    unsigned short* __restrict__ hbf, int blk,
    float* scr, float* thand, float (*tpart)[128])
{
  int tid = threadIdx.x;
  int half = tid >> 7, ch = tid & 127;
  int cidx = blk & (NC_ - 1);
  size_t base2 = (size_t)blk * (CH_ * 256);
  size_t baseh = (size_t)blk * (CH_ * H_);
  const float* stp = ua + base2 + 2 * ch;
  unsigned short* hp = hbf + baseh + ch;

  // ---- carry preamble ----
  {
    const float* tp = totIn + (size_t)(blk - cidx) * H_ + ch;
    float p0 = NEGINF_, p1 = NEGINF_;
    int i = half;
    for (; i + 2 < cidx; i += 4) {
      float a0 = tp[(size_t)i * H_];
      float a1 = tp[(size_t)(i + 2) * H_];
      p0 = lae_(p0, a0); p1 = lae_(p1, a1);
    }
    for (; i < cidx; i += 2) p0 = lae_(p0, tp[(size_t)i * H_]);
    tpart[half * 2][ch] = p0; tpart[half * 2 + 1][ch] = p1;
  }
  __syncthreads();

  if (half == 0) {
    float r = LOGHALF_;
    r = lae_(r, tpart[0][ch]); r = lae_(r, tpart[1][ch]);
    r = lae_(r, tpart[2][ch]); r = lae_(r, tpart[3][ch]);
    for (int i0 = 0; i0 < 32; i0 += 16) {
      float uv[16], av[16];
      #pragma unroll
      for (int i = 0; i < 16; ++i) {
        float2 v = *reinterpret_cast<const float2*>(stp + (size_t)(i0 + i) * 256);
        uv[i] = v.x; av[i] = v.y;
      }
      #pragma unroll
      for (int i = 0; i < 16; ++i) {
        r = lae_(r, uv[i]);
        hp[(size_t)(i0 + i) * H_] = f2bf_(sigm_(__expf(av[i] + r)));
      }
    }
    thand[ch] = r;
  } else {
    float r = NEGINF_;
    for (int i0 = 0; i0 < 32; i0 += 16) {
      float uv[16];
      #pragma unroll
      for (int i = 0; i < 16; ++i) uv[i] = stp[(size_t)(32 + i0 + i) * 256];
      #pragma unroll
      for (int i = 0; i < 16; ++i) { r = lae_(r, uv[i]); scr[(i0 + i) * 128 + ch] = r; }
    }
  }
  __syncthreads();
  if (half == 1) {
    float r31 = thand[ch];
    for (int i0 = 0; i0 < 32; i0 += 16) {
      float av[16];
      #pragma unroll
      for (int i = 0; i < 16; ++i) av[i] = stp[(size_t)(32 + i0 + i) * 256 + 1];
      #pragma unroll
      for (int i = 0; i < 16; ++i) {
        float ri = lae_(r31, scr[(i0 + i) * 128 + ch]);
        hp[(size_t)(32 + i0 + i) * H_] = f2bf_(sigm_(__expf(av[i] + ri)));
      }
    }
  }
}

// ---------------- fused cooperative: kb(l0->1) | kb(l1->2) | scan3 ----------
// grid = 1024 blocks (4/CU capacity at 35.8KB LDS), 2 chunks per block/stage.
__global__ __launch_bounds__(256, 4) void scans_kernel(
    const float* __restrict__ tot0,
    const unsigned short* __restrict__ Wc1,
    const float* __restrict__ bz1, const float* __restrict__ bh1,
    const unsigned short* __restrict__ Wc2,
    const float* __restrict__ bz2, const float* __restrict__ bh2,
    float* __restrict__ ua, float* __restrict__ tot1, float* __restrict__ tot2,
    unsigned short* __restrict__ hbf)
{
  __shared__ unsigned short hT[64][HTP_]; // 17.0 KB
  __shared__ float ksu[16 * 260];         // 16.25 KB (kg | scr union)
  __shared__ float thand[128];            // 0.5 KB
  __shared__ float tpart[4][128];         // 2 KB
  cg::grid_group grid = cg::this_grid();
  int b2 = blockIdx.x * 2;

  kb_body(tot0, Wc1, bz1, bh1, ua, tot1, b2,     hT, ksu, thand, tpart);
  __syncthreads();
  kb_body(tot0, Wc1, bz1, bh1, ua, tot1, b2 + 1, hT, ksu, thand, tpart);
  __threadfence();
  grid.sync();

  kb_body(tot1, Wc2, bz2, bh2, ua, tot2, b2,     hT, ksu, thand, tpart);
  __syncthreads();
  kb_body(tot1, Wc2, bz2, bh2, ua, tot2, b2 + 1, hT, ksu, thand, tpart);
  __threadfence();
  grid.sync();

  scan3_body(ua, tot2, hbf, b2,     ksu, thand, tpart);
  __syncthreads();
  scan3_body(ua, tot2, hbf, b2 + 1, ksu, thand, tpart);
}

// ---------------- fallback standalone kernels (proven path) -----------------
__global__ __launch_bounds__(256) void kb_kernel(
    const float* __restrict__ totIn, const unsigned short* __restrict__ Wc,
    const float* __restrict__ bz, const float* __restrict__ bh,
    float* __restrict__ ua, float* __restrict__ totOut)
{
  __shared__ unsigned short hT[64][HTP_];
  __shared__ float ksu[16 * 260];
  __shared__ float thand[128];
  __shared__ float tpart[4][128];
  kb_body(totIn, Wc, bz, bh, ua, totOut, blockIdx.x, hT, ksu, thand, tpart);
}

__global__ __launch_bounds__(256) void scan3v2_kernel(
    const float* __restrict__ ua, const float* __restrict__ totIn,
    unsigned short* __restrict__ hbf)
{
  __shared__ float scr[32 * 128];
  __shared__ float thand[128];
  __shared__ float tpart[4][128];
  scan3_body(ua, totIn, hbf, blockIdx.x, scr, thand, tpart);
}

// ---------------- final matmul: out[32,128] = h2flat @ Wout^T + bout --------
__device__ __forceinline__ void omload_(
    const unsigned short* ap0, const unsigned short* ap1,
    const float* wp0, const float* wp1, int k,
    bf16x8& a0r, bf16x8& a1r, float4 (&wr)[2][2])
{
  a0r = *reinterpret_cast<const bf16x8*>(ap0 + k);
  a1r = *reinterpret_cast<const bf16x8*>(ap1 + k);
  wr[0][0] = *reinterpret_cast<const float4*>(wp0 + k);
  wr[0][1] = *reinterpret_cast<const float4*>(wp0 + k + 4);
  wr[1][0] = *reinterpret_cast<const float4*>(wp1 + k);
  wr[1][1] = *reinterpret_cast<const float4*>(wp1 + k + 4);
}
__device__ __forceinline__ void omstep_(
    const bf16x8& a0r, const bf16x8& a1r,
    const float4 (&wr)[2][2], f32x4 (&acc)[2][2])
{
  #pragma unroll
  for (int nt = 0; nt < 2; ++nt) {
    ushort8_t tt;
    tt[0] = f2bf_(wr[nt][0].x); tt[1] = f2bf_(wr[nt][0].y);
    tt[2] = f2bf_(wr[nt][0].z); tt[3] = f2bf_(wr[nt][0].w);
    tt[4] = f2bf_(wr[nt][1].x); tt[5] = f2bf_(wr[nt][1].y);
    tt[6] = f2bf_(wr[nt][1].z); tt[7] = f2bf_(wr[nt][1].w);
    bf16x8 bfv = __builtin_bit_cast(bf16x8, tt);
    acc[0][nt] = __builtin_amdgcn_mfma_f32_16x16x32_bf16(a0r, bfv, acc[0][nt], 0, 0, 0);
    acc[1][nt] = __builtin_amdgcn_mfma_f32_16x16x32_bf16(a1r, bfv, acc[1][nt], 0, 0, 0);
  }
}

__global__ __launch_bounds__(256) void outmm_kernel(
    const unsigned short* __restrict__ hbf,  // 32 x 524288 bf16
    const float* __restrict__ Wout,          // 128 x 524288 fp32
    float* __restrict__ part)
{
  const int KSL = KTOT_ / NKS_;  // 1024
  int tid = threadIdx.x, w = tid >> 6, lane = tid & 63;
  int l15 = lane & 15, quad = lane >> 4;
  int k0base = blockIdx.x * KSL;
  const unsigned short* ap0 = hbf + (size_t)l15 * KTOT_ + k0base + quad * 8;
  const unsigned short* ap1 = hbf + (size_t)(16 + l15) * KTOT_ + k0base + quad * 8;
  const float* wp0 = Wout + (size_t)(w * 32 + l15) * KTOT_ + k0base + quad * 8;
  const float* wp1 = Wout + (size_t)(w * 32 + 16 + l15) * KTOT_ + k0base + quad * 8;
  f32x4 acc[2][2] = {{{0,0,0,0},{0,0,0,0}},{{0,0,0,0},{0,0,0,0}}};
  bf16x8 aA0, aA1, aB0, aB1;
  float4 wvA[2][2], wvB[2][2];
  omload_(ap0, ap1, wp0, wp1, 0, aA0, aA1, wvA);
  for (int ks = 0; ks < KSL; ks += 64) {
    omload_(ap0, ap1, wp0, wp1, ks + 32, aB0, aB1, wvB);
    omstep_(aA0, aA1, wvA, acc);
    if (ks + 64 < KSL) omload_(ap0, ap1, wp0, wp1, ks + 64, aA0, aA1, wvA);
    omstep_(aB0, aB1, wvB, acc);
  }
  float* pp = part + (size_t)blockIdx.x * (B_ * OUT_);
  #pragma unroll
  for (int mt = 0; mt < 2; ++mt)
    #pragma unroll
    for (int nt = 0; nt < 2; ++nt)
      #pragma unroll
      for (int r = 0; r < 4; ++r) {
        int b = mt * 16 + quad * 4 + r;
        int o = w * 32 + nt * 16 + l15;
        pp[b * OUT_ + o] = acc[mt][nt][r];
      }
}

// ---------------- coalesced split-K reduction ------------------------------
__global__ __launch_bounds__(256) void outred_kernel(
    const float* __restrict__ part, const float* __restrict__ bout,
    float* __restrict__ out)
{
  __shared__ float red[4][64];
  int w = threadIdx.x >> 6, lane = threadIdx.x & 63;
  int idx0 = blockIdx.x * 64;
  float s = 0.f;
  for (int wg = w; wg < NKS_; wg += 4)
    s += part[(size_t)wg * (B_ * OUT_) + idx0 + lane];
  red[w][lane] = s;
  __syncthreads();
  if (w == 0) {
    float r = (red[0][lane] + red[1][lane]) + (red[2][lane] + red[3][lane]);
    int idx = idx0 + lane;
    out[idx] = r + bout[idx & (OUT_ - 1)];
  }
}

// ---------------- host launcher ----------------
extern "C" void kernel_launch(void* const* d_in, const int* in_sizes, int n_in,
                              void* d_out, int out_size, void* d_ws, size_t ws_size,
                              hipStream_t stream)
{
  const float* x    = (const float*)d_in[0];
  const float* Wz[3] = {(const float*)d_in[1], (const float*)d_in[5], (const float*)d_in[9]};
  const float* bz[3] = {(const float*)d_in[2], (const float*)d_in[6], (const float*)d_in[10]};
  const float* Wh[3] = {(const float*)d_in[3], (const float*)d_in[7], (const float*)d_in[11]};
  const float* bh[3] = {(const float*)d_in[4], (const float*)d_in[8], (const float*)d_in[12]};
  const float* Wout = (const float*)d_in[13];
  const float* bout = (const float*)d_in[14];
  float* out = (float*)d_out;

  char* ws = (char*)d_ws;
  float*          ua    = (float*)(ws + 0);                  // 128 MiB {u,A}
  unsigned short* hbf   = (unsigned short*)(ws + 134217728); // 32 MiB
  unsigned short* Wc1   = (unsigned short*)(ws + 167772160); // 64 KiB
  unsigned short* Wc2   = (unsigned short*)(ws + 167837696); // 64 KiB
  float*          totA  = (float*)(ws + 167903232);          // 1 MiB
  float*          totB  = (float*)(ws + 168951808);          // 1 MiB
  float*          totC  = (float*)(ws + 170000384);          // 1 MiB
  float*          part  = (float*)(ws + 171048960);          // 8 MiB

  // layer 0 prep + totals (+ weight convert in tail blocks)
  prep0c_kernel<<<B_ * NC_ + 128, 256, 0, stream>>>(
      x, Wz[0], bz[0], Wh[0], bh[0], ua, totA,
      Wz[1], Wh[1], Wz[2], Wh[2], Wc1, Wc2);

  // fused cooperative scan phase (fallback: proven separate kernels)
  int coop = 0;
  {
    int maxb = 0;
    if (hipOccupancyMaxActiveBlocksPerMultiprocessor(
            &maxb, (const void*)scans_kernel, 256, 0) == hipSuccess &&
        maxb >= 4) {
      const float* tot0p = totA;
      const unsigned short* wc1p = Wc1;
      const float* bz1p = bz[1]; const float* bh1p = bh[1];
      const unsigned short* wc2p = Wc2;
      const float* bz2p = bz[2]; const float* bh2p = bh[2];
      float* uap = ua; float* t1p = totB; float* t2p = totC;
      unsigned short* hbfp = hbf;
      void* kargs[] = {(void*)&tot0p, (void*)&wc1p, (void*)&bz1p, (void*)&bh1p,
                       (void*)&wc2p, (void*)&bz2p, (void*)&bh2p,
                       (void*)&uap, (void*)&t1p, (void*)&t2p, (void*)&hbfp};
      if (hipLaunchCooperativeKernel((const void*)scans_kernel, dim3(1024),
                                     dim3(256), kargs, 0, stream) == hipSuccess)
        coop = 1;
    }
  }
  if (!coop) {
    kb_kernel<<<B_ * NC_, 256, 0, stream>>>(totA, Wc1, bz[1], bh[1], ua, totB);
    kb_kernel<<<B_ * NC_, 256, 0, stream>>>(totB, Wc2, bz[2], bh[2], ua, totC);
    scan3v2_kernel<<<B_ * NC_, 256, 0, stream>>>(ua, totC, hbf);
  }

  // output head
  outmm_kernel<<<NKS_, 256, 0, stream>>>(hbf, Wout, part);
  outred_kernel<<<(B_ * OUT_) / 64, 256, 0, stream>>>(part, bout, out);
}